// Round 4
// baseline (1227.583 us; speedup 1.0000x reference)
//
#include <hip/hip_runtime.h>
#include <limits.h>
#include <math.h>
#include <stdint.h>

// Problem constants (fixed by reference setup_inputs)
constexpr int D_ = 4;
constexpr int B_ = 8192;
constexpr int F_ = 128;
constexpr int BM = 64;             // rows per block
constexpr int BN = 64;             // cols per tile step
constexpr int NCT = B_ / BN;       // 128 col tiles total
constexpr int NPARTS = 3;          // column split factor
constexpr int TPP = 43;            // tiles per part (43,43,42)
constexpr float LO_SCALE = 4096.f; // 2^12 keeps lo out of f16 subnormals
constexpr float LO_INV = 1.f / 4096.f;

typedef _Float16 f16x8 __attribute__((ext_vector_type(8)));
typedef float f32x16 __attribute__((ext_vector_type(16)));

// C/D layout for mfma_f32_32x32x16 (m74/m101 verified):
//   col = lane&31, row = (reg&3) + 8*(reg>>2) + 4*(lane>>5)
__device__ __host__ constexpr int ROFS(int reg) { return (reg & 3) + 8 * (reg >> 2); }

// ---- pass 1: fp32 -> (hi, lo*4096) f16 split ----
__global__ __launch_bounds__(256)
void convert_f16(const float* __restrict__ src,
                 _Float16* __restrict__ hi, _Float16* __restrict__ lo) {
    const size_t i0 = ((size_t)blockIdx.x * 256 + threadIdx.x) * 8;
    const float4 a = *(const float4*)(src + i0);
    const float4 b = *(const float4*)(src + i0 + 4);
    const float xs[8] = {a.x, a.y, a.z, a.w, b.x, b.y, b.z, b.w};
    f16x8 h, l;
    #pragma unroll
    for (int k = 0; k < 8; ++k) {
        const _Float16 hh = (_Float16)xs[k];
        h[k] = hh;
        l[k] = (_Float16)((xs[k] - (float)hh) * LO_SCALE);
    }
    *(f16x8*)(hi + i0) = h;
    *(f16x8*)(lo + i0) = l;
}

// ---- pass 2: mine hardest pos/neg via 32x32x16 MFMA, partials to ws ----
// tuples layout: [d*B + row][part][wc] of uint4{pmin, nmax, (nidx16<<16)|pidx16, 0}
template <bool PRE>
__global__ __launch_bounds__(256, 3)
void mine_mfma(const float* __restrict__ emb,
               const _Float16* __restrict__ Ehi,
               const _Float16* __restrict__ Elo,
               const int* __restrict__ labels,
               uint4* __restrict__ tuples) {
    // swizzled B tile: slot(r, g) = r*16 + (g ^ (r&15)); 16 B per slot
    __shared__ f16x8 BhiS[1024];   // 16 KB
    __shared__ f16x8 BloS[1024];   // 16 KB

    const int tid = threadIdx.x;
    const int lane = tid & 63;
    const int wid = tid >> 6;
    const int wr = wid >> 1, wc = wid & 1;  // 2x2 wave grid, 32x32 out each
    const int l31 = lane & 31, h = lane >> 5;

    const int bid = blockIdx.x;
    const int p = bid >> 9;                // part 0..2
    const int r9 = bid & 511;
    const int d = r9 >> 7;
    const int rt = r9 & 127;
    const int row0 = rt * BM;

    const int ct0 = p * TPP;
    const int ct1 = (ct0 + TPP < NCT) ? ct0 + TPP : NCT;

    const float* __restrict__ embD = emb + (size_t)d * B_ * F_;
    const _Float16* __restrict__ EhiD = Ehi + (size_t)d * B_ * F_;
    const _Float16* __restrict__ EloD = Elo + (size_t)d * B_ * F_;
    const int* __restrict__ labD = labels + d * B_;

    // ---- A fragments in registers: lane holds A[row=l31][k = ks*16 + h*8 + e] ----
    const int arow = row0 + wr * 32 + l31;
    f16x8 Ah[8], Al[8];
    #pragma unroll
    for (int ks = 0; ks < 8; ++ks) {
        if constexpr (PRE) {
            Ah[ks] = *(const f16x8*)(EhiD + (size_t)arow * F_ + ks * 16 + h * 8);
            Al[ks] = *(const f16x8*)(EloD + (size_t)arow * F_ + ks * 16 + h * 8);
        } else {
            const float* pp = embD + (size_t)arow * F_ + ks * 16 + h * 8;
            const float4 x = *(const float4*)pp;
            const float4 y = *(const float4*)(pp + 4);
            const float xs[8] = {x.x, x.y, x.z, x.w, y.x, y.y, y.z, y.w};
            #pragma unroll
            for (int k = 0; k < 8; ++k) {
                const _Float16 hh = (_Float16)xs[k];
                Ah[ks][k] = hh;
                Al[ks][k] = (_Float16)((xs[k] - (float)hh) * LO_SCALE);
            }
        }
    }

    // ---- per-lane output rows (C layout) & labels, packed 4 x u8 per u32 ----
    // rows for (h, reg): rbase + ROFS(reg); reg=4q+j -> row rbase + 8q + j
    const int rbase = row0 + wr * 32 + 4 * h;
    uint32_t rlab4[4];
    #pragma unroll
    for (int q = 0; q < 4; ++q) {
        uint32_t v = 0;
        #pragma unroll
        for (int j = 0; j < 4; ++j)
            v |= ((uint32_t)labD[rbase + 8 * q + j] & 0xFFu) << (8 * j);
        rlab4[q] = v;
    }

    float pmin[16], nmax[16];
    int pidx[16], nidx[16];
    #pragma unroll
    for (int reg = 0; reg < 16; ++reg) {
        pmin[reg] = INFINITY;  pidx[reg] = INT_MAX;
        nmax[reg] = -INFINITY; nidx[reg] = INT_MAX;
    }

    // ---- staging slots: global-linear source, swizzled LDS dest ----
    int sr[4], sg[4], sslot[4];
    #pragma unroll
    for (int i = 0; i < 4; ++i) {
        const int flat = i * 256 + tid;
        sr[i] = flat >> 4;
        sg[i] = flat & 15;
        sslot[i] = sr[i] * 16 + (sg[i] ^ (sr[i] & 15));
    }

    f16x8 sh[4], sl[4];
    auto loadStage = [&](int ct) {
        #pragma unroll
        for (int i = 0; i < 4; ++i) {
            if constexpr (PRE) {
                sh[i] = *(const f16x8*)(EhiD + (size_t)(ct * 64 + sr[i]) * F_ + sg[i] * 8);
                sl[i] = *(const f16x8*)(EloD + (size_t)(ct * 64 + sr[i]) * F_ + sg[i] * 8);
            } else {
                const float* pp = embD + (size_t)(ct * 64 + sr[i]) * F_ + sg[i] * 8;
                const float4 x = *(const float4*)pp;
                const float4 y = *(const float4*)(pp + 4);
                const float xs[8] = {x.x, x.y, x.z, x.w, y.x, y.y, y.z, y.w};
                #pragma unroll
                for (int k = 0; k < 8; ++k) {
                    const _Float16 hh = (_Float16)xs[k];
                    sh[i][k] = hh;
                    sl[i][k] = (_Float16)((xs[k] - (float)hh) * LO_SCALE);
                }
            }
        }
    };
    auto writeStage = [&]() {
        #pragma unroll
        for (int i = 0; i < 4; ++i) {
            BhiS[sslot[i]] = sh[i];
            BloS[sslot[i]] = sl[i];
        }
    };

    const int brow = wc * 32 + l31;          // tile-local col (= B row)
    const int bswz = brow & 15;

    // ---- main loop: reg-staged double buffer, two barriers per tile ----
    loadStage(ct0);
    for (int ct = ct0; ct < ct1; ++ct) {
        __syncthreads();            // previous tile's LDS readers done
        writeStage();
        __syncthreads();            // tile visible to all waves
        if (ct + 1 < ct1) loadStage(ct + 1);   // issue-early (hide HBM/L2 latency)

        f32x16 a1, a2;
        #pragma unroll
        for (int q = 0; q < 16; ++q) { a1[q] = 0.f; a2[q] = 0.f; }

        #pragma unroll
        for (int ks = 0; ks < 8; ++ks) {
            const int g = 2 * ks + h;
            const f16x8 bh = BhiS[brow * 16 + (g ^ bswz)];
            const f16x8 bl = BloS[brow * 16 + (g ^ bswz)];
            a1 = __builtin_amdgcn_mfma_f32_32x32x16_f16(Ah[ks], bh, a1, 0, 0, 0);
            a2 = __builtin_amdgcn_mfma_f32_32x32x16_f16(Ah[ks], bl, a2, 0, 0, 0);
            a2 = __builtin_amdgcn_mfma_f32_32x32x16_f16(Al[ks], bh, a2, 0, 0, 0);
        }

        const int jl = ct * 64 + brow;       // domain-local col index
        const uint32_t clb = (uint32_t)labD[jl] & 0xFFu;

        #pragma unroll
        for (int reg = 0; reg < 16; ++reg) {
            const float s = fmaf(a2[reg], LO_INV, a1[reg]);
            const bool same = (((rlab4[reg >> 2] >> ((reg & 3) * 8)) & 0xFFu) == clb);
            const bool self = (jl == rbase + ROFS(reg));   // only true on diagonal
            const float ps = (same && !self) ? s : INFINITY;
            if (ps < pmin[reg]) { pmin[reg] = ps; pidx[reg] = jl; }
            const float ns = same ? -INFINITY : s;
            if (ns > nmax[reg]) { nmax[reg] = ns; nidx[reg] = jl; }
        }
    }

    // ---- in-half shfl reduce across the 32 col-lanes ----
    #pragma unroll
    for (int off = 1; off < 32; off <<= 1)
        #pragma unroll
        for (int reg = 0; reg < 16; ++reg) {
            float ov = __shfl_xor(pmin[reg], off);
            int oi = __shfl_xor(pidx[reg], off);
            if (ov < pmin[reg]) { pmin[reg] = ov; pidx[reg] = oi; }
            ov = __shfl_xor(nmax[reg], off);
            oi = __shfl_xor(nidx[reg], off);
            if (ov > nmax[reg]) { nmax[reg] = ov; nidx[reg] = oi; }
        }

    // ---- write partial tuples: lanes l31==reg (halves h=0,1 both write) ----
    #pragma unroll
    for (int reg = 0; reg < 16; ++reg) {
        if (l31 == reg) {
            const int row = rbase + ROFS(reg);
            const uint32_t pi = (pidx[reg] == INT_MAX) ? 0xFFFFu : (uint32_t)pidx[reg];
            const uint32_t ni = (nidx[reg] == INT_MAX) ? 0xFFFFu : (uint32_t)nidx[reg];
            uint4 t;
            t.x = __float_as_uint(pmin[reg]);
            t.y = __float_as_uint(nmax[reg]);
            t.z = pi | (ni << 16);
            t.w = 0u;
            tuples[(((size_t)d * B_ + row) * NPARTS + p) * 2 + wc] = t;
        }
    }
}

// ---- pass 3: merge partials, write dists, gather embeddings (exact fp32) ----
__global__ __launch_bounds__(256)
void merge_gather(const float* __restrict__ emb,
                  const uint4* __restrict__ tuples,
                  float* __restrict__ out) {
    const int tid = threadIdx.x;
    const int g = tid & 15;
    const int grp = tid >> 4;
    const int rowg = blockIdx.x * 16 + grp;     // global row 0..D*B-1
    const int d = rowg >> 13;                   // /8192

    float pmin = INFINITY, nmax = -INFINITY;
    int pidx = -1, nidx = -1;
    #pragma unroll
    for (int t = 0; t < NPARTS * 2; ++t) {
        const uint4 tp = tuples[(size_t)rowg * (NPARTS * 2) + t];
        const float pv = __uint_as_float(tp.x);
        const float nv = __uint_as_float(tp.y);
        const int pi = (int)(tp.z & 0xFFFFu);
        const int ni = (int)(tp.z >> 16);
        if (pi != 0xFFFF && (pidx < 0 || pv < pmin || (pv == pmin && pi < pidx))) {
            pmin = pv; pidx = pi;
        }
        if (ni != 0xFFFF && (nidx < 0 || nv > nmax || (nv == nmax && ni < nidx))) {
            nmax = nv; nidx = ni;
        }
    }

    float* __restrict__ pd = out;
    float* __restrict__ nd = out + (size_t)D_ * B_;
    float* __restrict__ pe = out + (size_t)2 * D_ * B_;
    float* __restrict__ ne = pe + (size_t)D_ * B_ * F_;

    const bool has = (pidx >= 0);
    if (g == 0) {
        pd[rowg] = has ? pmin : 0.f;
        nd[rowg] = has ? nmax : 0.f;
    }

    const float* __restrict__ embD = emb + (size_t)d * B_ * F_;
    const size_t ob = (size_t)rowg * F_;
    if (has) {
        const int ni2 = (nidx < 0) ? 0 : nidx;
        const float4* sp = (const float4*)(embD + (size_t)pidx * F_);
        const float4* sn = (const float4*)(embD + (size_t)ni2 * F_);
        *(float4*)(&pe[ob + g * 4]) = sp[g];             // 16 lanes x 16 B contiguous
        *(float4*)(&pe[ob + 64 + g * 4]) = sp[16 + g];
        *(float4*)(&ne[ob + g * 4]) = sn[g];
        *(float4*)(&ne[ob + 64 + g * 4]) = sn[16 + g];
    } else {
        const float4 zv = make_float4(0.f, 0.f, 0.f, 0.f);
        *(float4*)(&pe[ob + g * 4]) = zv;
        *(float4*)(&pe[ob + 64 + g * 4]) = zv;
        *(float4*)(&ne[ob + g * 4]) = zv;
        *(float4*)(&ne[ob + 64 + g * 4]) = zv;
    }
}

extern "C" void kernel_launch(void* const* d_in, const int* in_sizes, int n_in,
                              void* d_out, int out_size, void* d_ws, size_t ws_size,
                              hipStream_t stream) {
    const float* emb = (const float*)d_in[0];
    const int* labels = (const int*)d_in[1];
    float* out = (float*)d_out;

    const size_t NE = (size_t)D_ * B_ * F_;                       // 4,194,304
    const size_t TUP_BYTES = (size_t)D_ * B_ * NPARTS * 2 * 16;   // 6.29 MB
    uint4* tuples = (uint4*)d_ws;

    const bool pre_ok = ws_size >= TUP_BYTES + NE * 2 * sizeof(_Float16);  // 23.1 MB

    if (pre_ok) {
        _Float16* Ehi = (_Float16*)((char*)d_ws + TUP_BYTES);
        _Float16* Elo = Ehi + NE;
        convert_f16<<<dim3((unsigned)(NE / 2048)), 256, 0, stream>>>(emb, Ehi, Elo);
        mine_mfma<true><<<dim3(NPARTS * D_ * (B_ / BM)), 256, 0, stream>>>(
            emb, Ehi, Elo, labels, tuples);
    } else {
        mine_mfma<false><<<dim3(NPARTS * D_ * (B_ / BM)), 256, 0, stream>>>(
            emb, nullptr, nullptr, labels, tuples);
    }
    merge_gather<<<dim3(D_ * B_ / 16), 256, 0, stream>>>(emb, tuples, out);
}

// Round 5
// 699.948 us; speedup vs baseline: 1.7538x; 1.7538x over previous
//
#include <hip/hip_runtime.h>
#include <limits.h>
#include <math.h>
#include <stdint.h>

// Problem constants (fixed by reference setup_inputs)
constexpr int D_ = 4;
constexpr int B_ = 8192;
constexpr int F_ = 128;
constexpr int BM = 64;             // rows per block
constexpr int BN = 64;             // cols per tile step
constexpr int NCT = B_ / BN;       // 128 col tiles total
constexpr int NPARTS = 3;          // column split factor
constexpr int TPP = 43;            // tiles per part (43,43,42)
constexpr float LO_SCALE = 4096.f; // 2^12 keeps lo out of f16 subnormals
constexpr float LO_INV = 1.f / 4096.f;

typedef _Float16 f16x8 __attribute__((ext_vector_type(8)));
typedef float f32x16 __attribute__((ext_vector_type(16)));

// C/D layout for mfma_f32_32x32x16 (m74/m101 verified):
//   col = lane&31, row = (reg&3) + 8*(reg>>2) + 4*(lane>>5)
__device__ __host__ constexpr int ROFS(int reg) { return (reg & 3) + 8 * (reg >> 2); }

__device__ __forceinline__ void gl_lds16(const void* g, void* l) {
    __builtin_amdgcn_global_load_lds(
        (const __attribute__((address_space(1))) void*)g,
        (__attribute__((address_space(3))) void*)l, 16, 0, 0);
}

// ---- pass 1: fp32 -> (hi, lo*4096) f16 split ----
__global__ __launch_bounds__(256)
void convert_f16(const float* __restrict__ src,
                 _Float16* __restrict__ hi, _Float16* __restrict__ lo) {
    const size_t i0 = ((size_t)blockIdx.x * 256 + threadIdx.x) * 8;
    const float4 a = *(const float4*)(src + i0);
    const float4 b = *(const float4*)(src + i0 + 4);
    const float xs[8] = {a.x, a.y, a.z, a.w, b.x, b.y, b.z, b.w};
    f16x8 h, l;
    #pragma unroll
    for (int k = 0; k < 8; ++k) {
        const _Float16 hh = (_Float16)xs[k];
        h[k] = hh;
        l[k] = (_Float16)((xs[k] - (float)hh) * LO_SCALE);
    }
    *(f16x8*)(hi + i0) = h;
    *(f16x8*)(lo + i0) = l;
}

// ---- pass 2: mine hardest pos/neg via 32x32x16 MFMA, partials to ws ----
// tuples layout: [d*B + row][part][wc] of uint4{pmin, nmax, (nidx16<<16)|pidx16, 0}
__global__ __launch_bounds__(256, 3)
void mine_mfma(const _Float16* __restrict__ Ehi,
               const _Float16* __restrict__ Elo,
               const int* __restrict__ labels,
               uint4* __restrict__ tuples) {
    // swizzled B tile: granule slot(r, g) = r*16 + (g ^ (r&15)); 16 B per granule
    __shared__ f16x8 BhiS[1024];   // 16 KB
    __shared__ f16x8 BloS[1024];   // 16 KB

    const int tid = threadIdx.x;
    const int lane = tid & 63;
    const int wid = tid >> 6;
    const int wr = wid >> 1, wc = wid & 1;  // 2x2 wave grid, 32x32 out each
    const int l31 = lane & 31, h = lane >> 5;

    const int bid = blockIdx.x;
    const int p = bid >> 9;                // part 0..2
    const int r9 = bid & 511;
    const int d = r9 >> 7;
    const int rt = r9 & 127;
    const int row0 = rt * BM;

    const int ct0 = p * TPP;
    const int ct1 = (ct0 + TPP < NCT) ? ct0 + TPP : NCT;

    const _Float16* __restrict__ EhiD = Ehi + (size_t)d * B_ * F_;
    const _Float16* __restrict__ EloD = Elo + (size_t)d * B_ * F_;
    const int* __restrict__ labD = labels + d * B_;

    // ---- A fragments in registers: lane holds A[row=l31][k = ks*16 + h*8 + e] ----
    const int arow = row0 + wr * 32 + l31;
    f16x8 Ah[8], Al[8];
    #pragma unroll
    for (int ks = 0; ks < 8; ++ks) {
        Ah[ks] = *(const f16x8*)(EhiD + (size_t)arow * F_ + ks * 16 + h * 8);
        Al[ks] = *(const f16x8*)(EloD + (size_t)arow * F_ + ks * 16 + h * 8);
    }

    // ---- per-lane output rows (C layout) & labels, packed 4 x u8 per u32 ----
    const int rbase = row0 + wr * 32 + 4 * h;
    uint32_t rlab4[4];
    #pragma unroll
    for (int q = 0; q < 4; ++q) {
        uint32_t v = 0;
        #pragma unroll
        for (int j = 0; j < 4; ++j)
            v |= ((uint32_t)labD[rbase + 8 * q + j] & 0xFFu) << (8 * j);
        rlab4[q] = v;
    }

    float pmin[16], nmax[16];
    uint32_t pn[16];   // pidx low16, nidx high16; 0xFFFF = invalid
    #pragma unroll
    for (int reg = 0; reg < 16; ++reg) {
        pmin[reg] = INFINITY;
        nmax[reg] = -INFINITY;
        pn[reg] = 0xFFFFFFFFu;
    }

    // ---- staging: linear LDS dest, inverse-swizzled global source ----
    // dest granule G = i*256 + tid; r = G>>4, src granule = (G&15) ^ (r&15)
    // per-thread: r = i*16 + (tid>>4), srcg = (tid&15) ^ (tid>>4)  (i*16 ≡ 0 mod 16)
    const int sr0 = tid >> 4;
    const int sg = (tid & 15) ^ sr0;
    const size_t soff0 = (size_t)sr0 * F_ + sg * 8;   // f16 elements, i=0
    const int ldsbase = (wid << 6);                    // wave-uniform granule base

    auto stageWS = [&](int ct) {
        const size_t tb = (size_t)ct * BN * F_;
        #pragma unroll
        for (int i = 0; i < 4; ++i) {
            const size_t so = tb + soff0 + (size_t)i * 16 * F_;
            gl_lds16(EhiD + so, (void*)&BhiS[i * 256 + ldsbase]);
            gl_lds16(EloD + so, (void*)&BloS[i * 256 + ldsbase]);
        }
    };

    const int brow = wc * 32 + l31;          // tile-local col (= B row)
    const int bswz = l31 & 15;               // brow & 15

    for (int ct = ct0; ct < ct1; ++ct) {
        __syncthreads();            // all waves done reading previous tile
        stageWS(ct);
        __syncthreads();            // compiler drains vmcnt(0) before barrier

        f32x16 a1, a2;
        #pragma unroll
        for (int q = 0; q < 16; ++q) { a1[q] = 0.f; a2[q] = 0.f; }

        #pragma unroll
        for (int ks = 0; ks < 8; ++ks) {
            const int g = 2 * ks + h;
            const f16x8 bh = BhiS[(brow << 4) + (g ^ bswz)];
            const f16x8 bl = BloS[(brow << 4) + (g ^ bswz)];
            a1 = __builtin_amdgcn_mfma_f32_32x32x16_f16(Ah[ks], bh, a1, 0, 0, 0);
            a2 = __builtin_amdgcn_mfma_f32_32x32x16_f16(Ah[ks], bl, a2, 0, 0, 0);
            a2 = __builtin_amdgcn_mfma_f32_32x32x16_f16(Al[ks], bh, a2, 0, 0, 0);
        }

        const int jl = ct * 64 + brow;       // domain-local col index
        const uint32_t clb = (uint32_t)labD[jl] & 0xFFu;

        if (ct == rt) {                      // diagonal tile: exclude self (uniform branch)
            #pragma unroll
            for (int reg = 0; reg < 16; ++reg) {
                const float s = fmaf(a2[reg], LO_INV, a1[reg]);
                const bool same = (((rlab4[reg >> 2] >> ((reg & 3) * 8)) & 0xFFu) == clb);
                const bool self = (jl == rbase + ROFS(reg));
                const float ps = (same && !self) ? s : INFINITY;
                if (ps < pmin[reg]) { pmin[reg] = ps; pn[reg] = (pn[reg] & 0xFFFF0000u) | (uint32_t)jl; }
                const float ns = same ? -INFINITY : s;
                if (ns > nmax[reg]) { nmax[reg] = ns; pn[reg] = (pn[reg] & 0xFFFFu) | ((uint32_t)jl << 16); }
            }
        } else {
            #pragma unroll
            for (int reg = 0; reg < 16; ++reg) {
                const float s = fmaf(a2[reg], LO_INV, a1[reg]);
                const bool same = (((rlab4[reg >> 2] >> ((reg & 3) * 8)) & 0xFFu) == clb);
                const float ps = same ? s : INFINITY;
                if (ps < pmin[reg]) { pmin[reg] = ps; pn[reg] = (pn[reg] & 0xFFFF0000u) | (uint32_t)jl; }
                const float ns = same ? -INFINITY : s;
                if (ns > nmax[reg]) { nmax[reg] = ns; pn[reg] = (pn[reg] & 0xFFFFu) | ((uint32_t)jl << 16); }
            }
        }
    }

    // ---- in-half shfl reduce across the 32 col-lanes ----
    #pragma unroll
    for (int off = 1; off < 32; off <<= 1)
        #pragma unroll
        for (int reg = 0; reg < 16; ++reg) {
            const float opv = __shfl_xor(pmin[reg], off);
            const float onv = __shfl_xor(nmax[reg], off);
            const uint32_t opn = __shfl_xor((int)pn[reg], off);
            if (opv < pmin[reg]) { pmin[reg] = opv; pn[reg] = (pn[reg] & 0xFFFF0000u) | (opn & 0xFFFFu); }
            if (onv > nmax[reg]) { nmax[reg] = onv; pn[reg] = (pn[reg] & 0xFFFFu) | (opn & 0xFFFF0000u); }
        }

    // ---- write partial tuples: lanes l31==reg (both h halves write) ----
    #pragma unroll
    for (int reg = 0; reg < 16; ++reg) {
        if (l31 == reg) {
            const int row = rbase + ROFS(reg);
            uint4 t;
            t.x = __float_as_uint(pmin[reg]);
            t.y = __float_as_uint(nmax[reg]);
            t.z = pn[reg];
            t.w = 0u;
            tuples[(((size_t)d * B_ + row) * NPARTS + p) * 2 + wc] = t;
        }
    }
}

// ---- pass 3: merge partials, write dists, gather embeddings (exact fp32) ----
__global__ __launch_bounds__(256)
void merge_gather(const float* __restrict__ emb,
                  const uint4* __restrict__ tuples,
                  float* __restrict__ out) {
    const int tid = threadIdx.x;
    const int g = tid & 15;
    const int grp = tid >> 4;
    const int rowg = blockIdx.x * 16 + grp;     // global row 0..D*B-1
    const int d = rowg >> 13;                   // /8192

    float pmin = INFINITY, nmax = -INFINITY;
    int pidx = -1, nidx = -1;
    #pragma unroll
    for (int t = 0; t < NPARTS * 2; ++t) {
        const uint4 tp = tuples[(size_t)rowg * (NPARTS * 2) + t];
        const float pv = __uint_as_float(tp.x);
        const float nv = __uint_as_float(tp.y);
        const int pi = (int)(tp.z & 0xFFFFu);
        const int ni = (int)(tp.z >> 16);
        if (pi != 0xFFFF && (pidx < 0 || pv < pmin || (pv == pmin && pi < pidx))) {
            pmin = pv; pidx = pi;
        }
        if (ni != 0xFFFF && (nidx < 0 || nv > nmax || (nv == nmax && ni < nidx))) {
            nmax = nv; nidx = ni;
        }
    }

    float* __restrict__ pd = out;
    float* __restrict__ nd = out + (size_t)D_ * B_;
    float* __restrict__ pe = out + (size_t)2 * D_ * B_;
    float* __restrict__ ne = pe + (size_t)D_ * B_ * F_;

    const bool has = (pidx >= 0);
    if (g == 0) {
        pd[rowg] = has ? pmin : 0.f;
        nd[rowg] = has ? nmax : 0.f;
    }

    const float* __restrict__ embD = emb + (size_t)d * B_ * F_;
    const size_t ob = (size_t)rowg * F_;
    if (has) {
        const int ni2 = (nidx < 0) ? 0 : nidx;
        const float4* sp = (const float4*)(embD + (size_t)pidx * F_);
        const float4* sn = (const float4*)(embD + (size_t)ni2 * F_);
        *(float4*)(&pe[ob + g * 4]) = sp[g];             // 16 lanes x 16 B contiguous
        *(float4*)(&pe[ob + 64 + g * 4]) = sp[16 + g];
        *(float4*)(&ne[ob + g * 4]) = sn[g];
        *(float4*)(&ne[ob + 64 + g * 4]) = sn[16 + g];
    } else {
        const float4 zv = make_float4(0.f, 0.f, 0.f, 0.f);
        *(float4*)(&pe[ob + g * 4]) = zv;
        *(float4*)(&pe[ob + 64 + g * 4]) = zv;
        *(float4*)(&ne[ob + g * 4]) = zv;
        *(float4*)(&ne[ob + 64 + g * 4]) = zv;
    }
}

extern "C" void kernel_launch(void* const* d_in, const int* in_sizes, int n_in,
                              void* d_out, int out_size, void* d_ws, size_t ws_size,
                              hipStream_t stream) {
    const float* emb = (const float*)d_in[0];
    const int* labels = (const int*)d_in[1];
    float* out = (float*)d_out;

    const size_t NE = (size_t)D_ * B_ * F_;                       // 4,194,304
    const size_t TUP_BYTES = (size_t)D_ * B_ * NPARTS * 2 * 16;   // 3.1 MB
    uint4* tuples = (uint4*)d_ws;
    _Float16* Ehi = (_Float16*)((char*)d_ws + TUP_BYTES);
    _Float16* Elo = Ehi + NE;

    convert_f16<<<dim3((unsigned)(NE / 2048)), 256, 0, stream>>>(emb, Ehi, Elo);
    mine_mfma<<<dim3(NPARTS * D_ * (B_ / BM)), 256, 0, stream>>>(Ehi, Elo, labels, tuples);
    merge_gather<<<dim3(D_ * B_ / 16), 256, 0, stream>>>(emb, tuples, out);
}